// Round 6
// baseline (181.025 us; speedup 1.0000x reference)
//
#include <hip/hip_runtime.h>
#include <cstdint>
#include <cstddef>

typedef __attribute__((ext_vector_type(8))) short short8;     // 8 bf16 (4 VGPRs)
typedef __attribute__((ext_vector_type(4))) float f32x4;      // MFMA acc
typedef __attribute__((ext_vector_type(4))) unsigned short u16x4;

#define ASYNC16(gp, lp) \
  __builtin_amdgcn_global_load_lds((const __attribute__((address_space(1))) unsigned int*)(gp), \
                                   (__attribute__((address_space(3))) unsigned int*)(lp), 16, 0, 0)

__device__ __forceinline__ unsigned short f2b(float f) {
  union { float f; unsigned int u; } c; c.f = f;
  unsigned int u = c.u;
  return (unsigned short)((u + 0x7fffu + ((u >> 16) & 1u)) >> 16);
}

// ---------------- merged prep: x->bf16, w_attn->waT, w_proj->wpT ----------------

__global__ __launch_bounds__(256) void prep(
    const float* __restrict__ x, unsigned short* __restrict__ xb,
    const float* __restrict__ w_attn, unsigned short* __restrict__ waT,
    const float* __restrict__ w_proj, unsigned short* __restrict__ wpT) {
  __shared__ unsigned short Ts[64][65];
  const int bb = blockIdx.x;
  const int tid = threadIdx.x;
  if (bb < 3072) {
    int i = (bb * 256 + tid) * 8;
    const float* px = x + i;
    short8 v;
    for (int e = 0; e < 8; ++e) ((unsigned short*)&v)[e] = f2b(px[e]);
    *(short8*)(xb + i) = v;
    return;
  }
  const float* W; unsigned short* WT; int Kd, Nd, n0, k0;
  if (bb < 3504) {
    int t = bb - 3072; W = w_attn; WT = waT; Kd = 768; Nd = 2304;
    n0 = (t % 36) * 64; k0 = (t / 36) * 64;
  } else {
    int t = bb - 3504; W = w_proj; WT = wpT; Kd = 768; Nd = 768;
    n0 = (t % 12) * 64; k0 = (t / 12) * 64;
  }
  for (int idx = tid; idx < 4096; idx += 256) {
    int lr = idx >> 6, lc = idx & 63;
    Ts[lr][lc] = f2b(W[(size_t)(k0 + lr) * Nd + n0 + lc]);
  }
  __syncthreads();
  for (int idx = tid; idx < 4096; idx += 256) {
    int nr = idx >> 6, kc = idx & 63;
    WT[(size_t)(n0 + nr) * Kd + k0 + kc] = Ts[kc][nr];
  }
}

// ---------------- GEMM 1: qkv = x @ w_attn + b, scatter to q/k/vT ----------------
// R6: R0's proven 3-deep BK=32 skeleton (one barrier/step, 2-ahead counted
// vmcnt(4)) + the R3 both-sides XOR swizzle re-derived for 64B rows:
//   staging source chunk = (t&3) ^ ((t>>3)&3)   [involution on (R>>1)&3]
//   read chunk           = lq ^ ((lr>>1)&3)
// bank-quad(lane) = 4*(lr&1) + lq^((lr>>1)&3): 8 distinct quads / 16 lanes,
// 2 lanes/quad = free. LDS 3*(8KB+8KB) = 48KB -> 3 blocks/CU (R3 had 2);
// the extra resident block hides the per-step barrier/vmcnt stall that is
// ~45% of R3's cycles. R4 lesson: do NOT trade occupancy for phase depth.

__global__ __launch_bounds__(256, 3) void gemm_qkv(
    const unsigned short* __restrict__ A,   // xb [8192][768]
    const unsigned short* __restrict__ Bt,  // waT [2304][768]
    const float* __restrict__ bias,         // [2304]
    unsigned short* __restrict__ q,         // [96][1024][64], pre-scaled by 0.125*log2(e)
    unsigned short* __restrict__ k,         // [96][1024][64]
    unsigned short* __restrict__ vT)        // [96][64][1024]
{
  __shared__ unsigned short As[3][128 * 32];  // 8KB sub-tiles, 3-deep
  __shared__ unsigned short Bs[3][128 * 32];
  const int tid = threadIdx.x;
  const int w = tid >> 6, lane = tid & 63;
  const int wm = w >> 1, wn = w & 1;
  const int lr = lane & 15, lq = lane >> 4;

  const int bid = blockIdx.x;               // 1152 = 8 xcd * (18 y * 8 x)
  const int xcd = bid & 7;
  const int local = bid >> 3;
  const int ty = local >> 3;
  const int tx = xcd * 8 + (local & 7);
  const int m0 = tx * 128, n0 = ty * 128;
  const f32x4 fzero = {0.f, 0.f, 0.f, 0.f};

  f32x4 acc[4][4];
  for (int i = 0; i < 4; ++i) for (int j = 0; j < 4; ++j) acc[i][j] = fzero;

  // staging: thread t owns LDS chunks {t, t+256}; chunk L=(R,c): R=L>>2, c=L&3.
  // content rule LDS(R,c) = global(R, c ^ ((R>>1)&3)); (R>>1)&3 == (t>>3)&3
  // for both of t's chunks (row +64 leaves it unchanged: 64>>1 = 32 ≡ 0 mod 4).
  const int trow = tid >> 2;                      // 0..63 (+64 for chunk t+256)
  const int gc = (tid & 3) ^ ((tid >> 3) & 3);
  const unsigned short* Asrc = A + (size_t)(m0 + trow) * 768 + gc * 8;
  const unsigned short* Bsrc = Bt + (size_t)(n0 + trow) * 768 + gc * 8;
  const int dst0 = tid * 16;                      // dest byte (linear)

#define STAGE_QKV(s, bidx) do { \
    const unsigned short* as_ = Asrc + (s) * 32; \
    const unsigned short* bs_ = Bsrc + (s) * 32; \
    ASYNC16(as_,            (char*)As[bidx] + dst0); \
    ASYNC16(as_ + 64 * 768, (char*)As[bidx] + dst0 + 4096); \
    ASYNC16(bs_,            (char*)Bs[bidx] + dst0); \
    ASYNC16(bs_ + 64 * 768, (char*)Bs[bidx] + dst0 + 4096); \
  } while (0)

  STAGE_QKV(0, 0);
  STAGE_QKV(1, 1);

  // read: logical (R, k-chunk lq) -> LDS chunk (lq ^ ((R>>1)&3)); row terms
  // other than lr are ≡ 0 mod 4 after >>1, so the XOR is (lr>>1)&3.
  const int swz = (lq ^ ((lr >> 1) & 3)) * 16;    // chunk byte within 64B row
  const int arow = (wm * 64 + lr) * 64;           // + i*1024
  const int brow = (wn * 64 + lr) * 64;           // + j*1024

  int bi = 0;
  for (int s = 0; s < 24; ++s) {
    if (s < 23) asm volatile("s_waitcnt vmcnt(4)" ::: "memory");   // stage(s) landed
    else        asm volatile("s_waitcnt vmcnt(0)" ::: "memory");
    __builtin_amdgcn_s_barrier();      // step s-1 reads retired in all waves
    __builtin_amdgcn_sched_barrier(0);
    if (s + 2 < 24) {
      int b2 = bi + 2; if (b2 >= 3) b2 -= 3;
      STAGE_QKV(s + 2, b2);            // overwrites buf last read at step s-1
    }
    const char* asb = (const char*)As[bi];
    const char* bsb = (const char*)Bs[bi];
    short8 a[4], b[4];
    for (int i = 0; i < 4; ++i)
      a[i] = *(const short8*)(asb + arow + i * 1024 + swz);
    for (int j = 0; j < 4; ++j)
      b[j] = *(const short8*)(bsb + brow + j * 1024 + swz);
    for (int i = 0; i < 4; ++i)
      for (int j = 0; j < 4; ++j)
        acc[i][j] = __builtin_amdgcn_mfma_f32_16x16x32_bf16(a[i], b[j], acc[i][j], 0, 0, 0);
    ++bi; if (bi == 3) bi = 0;
  }
#undef STAGE_QKV

  const int colbase = n0 + wn * 64;
  const int sec = colbase / 768;                // 0=q, 1=k, 2=v (wave-uniform)
  const float QSCALE = 0.18033688011112042f;    // 0.125 * log2(e)
  for (int j = 0; j < 4; ++j) {
    int col = colbase + j * 16 + lr;
    int cc = col - sec * 768;
    int h = cc >> 6, d = cc & 63;
    float bv = bias[col];
    for (int i = 0; i < 4; ++i) {
      int row0 = m0 + wm * 64 + i * 16 + lq * 4;
      int bidx = row0 >> 10, t0 = row0 & 1023;
      int bh = bidx * 12 + h;
      if (sec == 0) {
        for (int r = 0; r < 4; ++r)
          q[((size_t)bh * 1024 + t0 + r) * 64 + d] = f2b((acc[i][j][r] + bv) * QSCALE);
      } else if (sec == 1) {
        for (int r = 0; r < 4; ++r)
          k[((size_t)bh * 1024 + t0 + r) * 64 + d] = f2b(acc[i][j][r] + bv);
      } else {
        u16x4 pv;
        pv[0] = f2b(acc[i][j][0] + bv);
        pv[1] = f2b(acc[i][j][1] + bv);
        pv[2] = f2b(acc[i][j][2] + bv);
        pv[3] = f2b(acc[i][j][3] + bv);
        *(u16x4*)(vT + ((size_t)bh * 64 + d) * 1024 + t0) = pv;
      }
    }
  }
}

// ---------------- flash attention, dual-Q-tile over one K/V stream ----------------
// R5 version (Q-hoist + setprio; measured null vs R3 but keeps fewer LDS reads).

__global__ __launch_bounds__(256, 3) void attn(
    const unsigned short* __restrict__ q,
    const unsigned short* __restrict__ kk,
    const unsigned short* __restrict__ vT,
    unsigned short* __restrict__ y)         // [8192][768]
{
  __shared__ unsigned short Qs[128 * 72];   // strip0 rows 0-63, strip1 rows 64-127
  __shared__ unsigned short Ks[64 * 72];
  __shared__ unsigned short Vt[64 * 72];    // [d][t]
  __shared__ unsigned short Ps[4 * 16 * 72];

  const int tid = threadIdx.x;
  const int w = tid >> 6, lane = tid & 63;
  const int lr = lane & 15, lq = lane >> 4;

  // 768 blocks = 8 xcd * (12 heads * 8 strips); strips of one head adjacent
  const int bid = blockIdx.x;
  const int xcd = bid & 7;
  const int local = bid >> 3;               // 0..95
  const int bh = xcd + 8 * (local >> 3);    // 0..95
  const int qp = local & 7;                 // strip0 tile 0..7
  const int qt1 = 15 - qp;                  // strip1 tile
  const int b = bh / 12, h = bh - b * 12;
  const f32x4 fzero = {0.f, 0.f, 0.f, 0.f};

  unsigned short* Pw = Ps + w * 16 * 72;
  const unsigned short* kbase = kk + (size_t)bh * 65536;
  const unsigned short* vbase = vT + (size_t)bh * 65536;

  {
    const unsigned short* qa = q + ((size_t)bh * 1024 + qp * 64) * 64;
    const unsigned short* qb = q + ((size_t)bh * 1024 + qt1 * 64) * 64;
    for (int c = tid; c < 512; c += 256) {
      int row = c >> 3, d0 = (c & 7) * 8;
      *(short8*)(Qs + row * 72 + d0)        = *(const short8*)(qa + (size_t)c * 8);
      *(short8*)(Qs + (row + 64) * 72 + d0) = *(const short8*)(qb + (size_t)c * 8);
    }
  }
  __syncthreads();
  // Q-hoist: per-wave Q fragments are fixed for the whole K-loop
  short8 qf0[2], qf1[2];
  for (int ks = 0; ks < 2; ++ks) {
    qf0[ks] = *(const short8*)(Qs + (w * 16 + lr) * 72 + ks * 32 + lq * 8);
    qf1[ks] = *(const short8*)(Qs + (64 + w * 16 + lr) * 72 + ks * 32 + lq * 8);
  }

  const int c0 = tid, c1 = tid + 256;
  short8 kreg[2], vreg[2];
  kreg[0] = *(const short8*)(kbase + (size_t)c0 * 8);
  kreg[1] = *(const short8*)(kbase + (size_t)c1 * 8);
  vreg[0] = *(const short8*)(vbase + (size_t)(c0 >> 3) * 1024 + (c0 & 7) * 8);
  vreg[1] = *(const short8*)(vbase + (size_t)(c1 >> 3) * 1024 + (c1 & 7) * 8);

  f32x4 o0[4], o1[4];
  float l0[4], l1[4];
  for (int jd = 0; jd < 4; ++jd) { o0[jd] = fzero; o1[jd] = fzero; }
  for (int r = 0; r < 4; ++r) { l0[r] = 0.0f; l1[r] = 0.0f; }

  const int nkt = qt1 + 1;

  for (int kt = 0; kt < nkt; ++kt) {
    __syncthreads();
    *(short8*)(Ks + (c0 >> 3) * 72 + (c0 & 7) * 8) = kreg[0];
    *(short8*)(Ks + (c1 >> 3) * 72 + (c1 & 7) * 8) = kreg[1];
    *(short8*)(Vt + (c0 >> 3) * 72 + (c0 & 7) * 8) = vreg[0];
    *(short8*)(Vt + (c1 >> 3) * 72 + (c1 & 7) * 8) = vreg[1];
    __syncthreads();
    if (kt + 1 < nkt) {
      const unsigned short* kp = kbase + (size_t)(kt + 1) * 4096;
      const unsigned short* vp = vbase + (size_t)(kt + 1) * 64;
      kreg[0] = *(const short8*)(kp + (size_t)c0 * 8);
      kreg[1] = *(const short8*)(kp + (size_t)c1 * 8);
      vreg[0] = *(const short8*)(vp + (size_t)(c0 >> 3) * 1024 + (c0 & 7) * 8);
      vreg[1] = *(const short8*)(vp + (size_t)(c1 >> 3) * 1024 + (c1 & 7) * 8);
    }

    short8 bk[2][4];
    for (int ks = 0; ks < 2; ++ks)
      for (int j = 0; j < 4; ++j)
        bk[ks][j] = *(const short8*)(Ks + (j * 16 + lr) * 72 + ks * 32 + lq * 8);

    if (kt <= qp) {                         // strip 0 (block-uniform branch)
      f32x4 s[4];
      for (int j = 0; j < 4; ++j) s[j] = fzero;
      __builtin_amdgcn_s_setprio(1);
      for (int ks = 0; ks < 2; ++ks) {
        for (int j = 0; j < 4; ++j)
          s[j] = __builtin_amdgcn_mfma_f32_16x16x32_bf16(qf0[ks], bk[ks][j], s[j], 0, 0, 0);
      }
      __builtin_amdgcn_s_setprio(0);
      if (kt == qp) {
        int rowt = w * 16 + lq * 4;
        for (int j = 0; j < 4; ++j) {
          int colt = j * 16 + lr;
          for (int r = 0; r < 4; ++r)
            if (colt > rowt + r) s[j][r] = -1e30f;
        }
      }
      for (int r = 0; r < 4; ++r) {
        int prow = (lq * 4 + r) * 72;
        float acc = 0.0f;
        for (int j = 0; j < 4; ++j) {
          float p = __builtin_amdgcn_exp2f(s[j][r]);
          acc += p;
          union { float f; unsigned int u; } cv; cv.f = p;
          Pw[prow + j * 16 + lr] = (unsigned short)((cv.u + 0x8000u) >> 16);
        }
        l0[r] += acc;
      }
      __builtin_amdgcn_s_setprio(1);
      for (int ks = 0; ks < 2; ++ks) {
        short8 ap = *(const short8*)(Pw + lr * 72 + ks * 32 + lq * 8);
        short8 bv[4];
        for (int jd = 0; jd < 4; ++jd)
          bv[jd] = *(const short8*)(Vt + (jd * 16 + lr) * 72 + ks * 32 + lq * 8);
        for (int jd = 0; jd < 4; ++jd)
          o0[jd] = __builtin_amdgcn_mfma_f32_16x16x32_bf16(ap, bv[jd], o0[jd], 0, 0, 0);
      }
      __builtin_amdgcn_s_setprio(0);
    }

    {                                       // strip 1 (always active)
      f32x4 s[4];
      for (int j = 0; j < 4; ++j) s[j] = fzero;
      __builtin_amdgcn_s_setprio(1);
      for (int ks = 0; ks < 2; ++ks) {
        for (int j = 0; j < 4; ++j)
          s[j] = __builtin_amdgcn_mfma_f32_16x16x32_bf16(qf1[ks], bk[ks][j], s[j], 0, 0, 0);
      }
      __builtin_amdgcn_s_setprio(0);
      if (kt == qt1) {
        int rowt = w * 16 + lq * 4;
        for (int j = 0; j < 4; ++j) {
          int colt = j * 16 + lr;
          for (int r = 0; r < 4; ++r)
            if (colt > rowt + r) s[j][r] = -1e30f;
        }
      }
      for (int r = 0; r < 4; ++r) {
        int prow = (lq * 4 + r) * 72;
        float acc = 0.0f;
        for (int j = 0; j < 4; ++j) {
          float p = __builtin_amdgcn_exp2f(s[j][r]);
          acc += p;
          union { float f; unsigned int u; } cv; cv.f = p;
          Pw[prow + j * 16 + lr] = (unsigned short)((cv.u + 0x8000u) >> 16);
        }
        l1[r] += acc;
      }
      __builtin_amdgcn_s_setprio(1);
      for (int ks = 0; ks < 2; ++ks) {
        short8 ap = *(const short8*)(Pw + lr * 72 + ks * 32 + lq * 8);
        short8 bv[4];
        for (int jd = 0; jd < 4; ++jd)
          bv[jd] = *(const short8*)(Vt + (jd * 16 + lr) * 72 + ks * 32 + lq * 8);
        for (int jd = 0; jd < 4; ++jd)
          o1[jd] = __builtin_amdgcn_mfma_f32_16x16x32_bf16(ap, bv[jd], o1[jd], 0, 0, 0);
      }
      __builtin_amdgcn_s_setprio(0);
    }
  }

  for (int r = 0; r < 4; ++r) {
    float a0 = l0[r], a1 = l1[r];
    for (int off = 1; off < 16; off <<= 1) {
      a0 += __shfl_xor(a0, off, 16);
      a1 += __shfl_xor(a1, off, 16);
    }
    l0[r] = 1.0f / a0;
    l1[r] = 1.0f / a1;
  }
  int t0 = qp * 64 + w * 16 + lq * 4;
  int t1 = qt1 * 64 + w * 16 + lq * 4;
  for (int jd = 0; jd < 4; ++jd) {
    int d = jd * 16 + lr;
    for (int r = 0; r < 4; ++r) {
      y[((size_t)b * 1024 + t0 + r) * 768 + h * 64 + d] = f2b(o0[jd][r] * l0[r]);
      y[((size_t)b * 1024 + t1 + r) * 768 + h * 64 + d] = f2b(o1[jd][r] * l1[r]);
    }
  }
}

// ---------------- GEMM 2: out = y @ w_proj + b ----------------
// R3 structure unchanged (swizzled BK=64, 2-deep, vmcnt(6)).

__global__ __launch_bounds__(256, 3) void gemm_proj(
    const unsigned short* __restrict__ A,   // y [8192][768]
    const unsigned short* __restrict__ Bt,  // wpT [768][768]
    const float* __restrict__ bias,         // [768]
    float* __restrict__ out)                // [8192][768] fp32
{
  __shared__ unsigned short As[2][64 * 64];   // 8KB sub-tiles
  __shared__ unsigned short Bs[2][128 * 64];  // 16KB sub-tiles
  const int tid = threadIdx.x;
  const int w = tid >> 6, lane = tid & 63;
  const int wm = w >> 1, wn = w & 1;        // wave-tile 32 x 64
  const int lr = lane & 15, lq = lane >> 4;

  // 768 blocks = 8 xcd * (6 y * 16 x)
  const int bid = blockIdx.x;
  const int xcd = bid & 7;
  const int local = bid >> 3;               // 0..95
  const int ty = local >> 4;                // 0..5
  const int tx = xcd * 16 + (local & 15);   // 0..127
  const int m0 = tx * 64, n0 = ty * 128;
  const f32x4 fzero = {0.f, 0.f, 0.f, 0.f};

  f32x4 acc[2][4];
  for (int i = 0; i < 2; ++i) for (int j = 0; j < 4; ++j) acc[i][j] = fzero;

  const int trow = tid >> 3;                // 0..31
  const int tcol = (tid & 7) ^ (trow & 7);
  const unsigned short* Asrc = A + (size_t)(m0 + trow) * 768 + tcol * 8;
  const unsigned short* Bsrc = Bt + (size_t)(n0 + trow) * 768 + tcol * 8;
  const int dst0 = tid * 16;

#define STAGE_PROJ(s, bidx) do { \
    const unsigned short* as_ = Asrc + (s) * 64; \
    const unsigned short* bs_ = Bsrc + (s) * 64; \
    ASYNC16(as_,            (char*)As[bidx] + dst0); \
    ASYNC16(as_ + 32 * 768, (char*)As[bidx] + dst0 + 4096); \
    ASYNC16(bs_,            (char*)Bs[bidx] + dst0); \
    ASYNC16(bs_ + 32 * 768, (char*)Bs[bidx] + dst0 + 4096); \
    ASYNC16(bs_ + 64 * 768, (char*)Bs[bidx] + dst0 + 8192); \
    ASYNC16(bs_ + 96 * 768, (char*)Bs[bidx] + dst0 + 12288); \
  } while (0)

  STAGE_PROJ(0, 0);

  const int swz = (lq ^ (lr & 7)) * 16;
  const int arow = (wm * 32 + lr) * 128;    // + i*2048
  const int brow = (wn * 64 + lr) * 128;    // + j*2048

  for (int s = 0; s < 12; ++s) {
    __builtin_amdgcn_s_barrier();
    if (s + 1 < 12) {
      STAGE_PROJ(s + 1, (s + 1) & 1);
      asm volatile("s_waitcnt vmcnt(6)" ::: "memory");
    } else {
      asm volatile("s_waitcnt vmcnt(0)" ::: "memory");
    }
    __builtin_amdgcn_s_barrier();
    __builtin_amdgcn_sched_barrier(0);
    const char* asb = (const char*)As[s & 1];
    const char* bsb = (const char*)Bs[s & 1];
    for (int ks = 0; ks < 2; ++ks) {
      const int cb = swz ^ (ks << 6);
      short8 a[2], b[4];
      for (int i = 0; i < 2; ++i)
        a[i] = *(const short8*)(asb + arow + i * 2048 + cb);
      for (int j = 0; j < 4; ++j)
        b[j] = *(const short8*)(bsb + brow + j * 2048 + cb);
      for (int i = 0; i < 2; ++i)
        for (int j = 0; j < 4; ++j)
          acc[i][j] = __builtin_amdgcn_mfma_f32_16x16x32_bf16(a[i], b[j], acc[i][j], 0, 0, 0);
    }
  }
#undef STAGE_PROJ

  for (int j = 0; j < 4; ++j) {
    int col = n0 + wn * 64 + j * 16 + lr;
    float bv = bias[col];
    for (int i = 0; i < 2; ++i) {
      int row0 = m0 + wm * 32 + i * 16 + lq * 4;
      for (int r = 0; r < 4; ++r)
        out[(size_t)(row0 + r) * 768 + col] = acc[i][j][r] + bv;
    }
  }
}

// ---------------- launch ----------------

extern "C" void kernel_launch(void* const* d_in, const int* in_sizes, int n_in,
                              void* d_out, int out_size, void* d_ws, size_t ws_size,
                              hipStream_t stream) {
  const float* x      = (const float*)d_in[0];
  const float* w_attn = (const float*)d_in[1];
  const float* b_attn = (const float*)d_in[2];
  const float* w_proj = (const float*)d_in[3];
  const float* b_proj = (const float*)d_in[4];
  float* out = (float*)d_out;

  char* p = (char*)d_ws;
  unsigned short* xb  = (unsigned short*)p; p += (size_t)8192 * 768 * 2;
  unsigned short* waT = (unsigned short*)p; p += (size_t)2304 * 768 * 2;
  unsigned short* wpT = (unsigned short*)p; p += (size_t)768 * 768 * 2;
  unsigned short* qb  = (unsigned short*)p; p += (size_t)96 * 1024 * 64 * 2;
  unsigned short* kb  = (unsigned short*)p; p += (size_t)96 * 1024 * 64 * 2;
  unsigned short* vTb = (unsigned short*)p; p += (size_t)96 * 64 * 1024 * 2;
  unsigned short* yb  = (unsigned short*)p; p += (size_t)8192 * 768 * 2;

  prep<<<3648, 256, 0, stream>>>(x, xb, w_attn, waT, w_proj, wpT);
  gemm_qkv<<<1152, 256, 0, stream>>>(xb, waT, b_attn, qb, kb, vTb);
  attn<<<768, 256, 0, stream>>>(qb, kb, vTb, yb);
  gemm_proj<<<768, 256, 0, stream>>>(yb, wpT, b_proj, out);
}

// Round 7
// 172.393 us; speedup vs baseline: 1.0501x; 1.0501x over previous
//
#include <hip/hip_runtime.h>
#include <cstdint>
#include <cstddef>

typedef __attribute__((ext_vector_type(8))) short short8;     // 8 bf16 (4 VGPRs)
typedef __attribute__((ext_vector_type(4))) float f32x4;      // MFMA acc
typedef __attribute__((ext_vector_type(4))) unsigned short u16x4;

#define ASYNC16(gp, lp) \
  __builtin_amdgcn_global_load_lds((const __attribute__((address_space(1))) unsigned int*)(gp), \
                                   (__attribute__((address_space(3))) unsigned int*)(lp), 16, 0, 0)

__device__ __forceinline__ unsigned short f2b(float f) {
  union { float f; unsigned int u; } c; c.f = f;
  unsigned int u = c.u;
  return (unsigned short)((u + 0x7fffu + ((u >> 16) & 1u)) >> 16);
}

// ---------------- merged prep: x->bf16, w_attn->waT, w_proj->wpT ----------------

__global__ __launch_bounds__(256) void prep(
    const float* __restrict__ x, unsigned short* __restrict__ xb,
    const float* __restrict__ w_attn, unsigned short* __restrict__ waT,
    const float* __restrict__ w_proj, unsigned short* __restrict__ wpT) {
  __shared__ unsigned short Ts[64][65];
  const int bb = blockIdx.x;
  const int tid = threadIdx.x;
  if (bb < 3072) {
    int i = (bb * 256 + tid) * 8;
    const float* px = x + i;
    short8 v;
    for (int e = 0; e < 8; ++e) ((unsigned short*)&v)[e] = f2b(px[e]);
    *(short8*)(xb + i) = v;
    return;
  }
  const float* W; unsigned short* WT; int Kd, Nd, n0, k0;
  if (bb < 3504) {
    int t = bb - 3072; W = w_attn; WT = waT; Kd = 768; Nd = 2304;
    n0 = (t % 36) * 64; k0 = (t / 36) * 64;
  } else {
    int t = bb - 3504; W = w_proj; WT = wpT; Kd = 768; Nd = 768;
    n0 = (t % 12) * 64; k0 = (t / 12) * 64;
  }
  for (int idx = tid; idx < 4096; idx += 256) {
    int lr = idx >> 6, lc = idx & 63;
    Ts[lr][lc] = f2b(W[(size_t)(k0 + lr) * Nd + n0 + lc]);
  }
  __syncthreads();
  for (int idx = tid; idx < 4096; idx += 256) {
    int nr = idx >> 6, kc = idx & 63;
    WT[(size_t)(n0 + nr) * Kd + k0 + kc] = Ts[kc][nr];
  }
}

// ---------------- GEMM 1: qkv = x @ w_attn + b, scatter to q/k/vT ----------------
// R3 structure EXACT (proven local optimum: 45.4us, conflicts 0).
// Experiment matrix closed: BK=64/2-deep/2blk = 45.4 beats BK=32/3-deep/3blk
// (59.4, R6) and 4-phase/1blk (67, R4). Do not touch the schedule again.

__global__ __launch_bounds__(256, 2) void gemm_qkv(
    const unsigned short* __restrict__ A,   // xb [8192][768]
    const unsigned short* __restrict__ Bt,  // waT [2304][768]
    const float* __restrict__ bias,         // [2304]
    unsigned short* __restrict__ q,         // [96][1024][64], pre-scaled by 0.125*log2(e)
    unsigned short* __restrict__ k,         // [96][1024][64]
    unsigned short* __restrict__ vT)        // [96][64][1024]
{
  __shared__ unsigned short As[2][128 * 64];  // 16KB sub-tiles (128 rows x 128B)
  __shared__ unsigned short Bs[2][128 * 64];
  const int tid = threadIdx.x;
  const int w = tid >> 6, lane = tid & 63;
  const int wm = w >> 1, wn = w & 1;
  const int lr = lane & 15, lq = lane >> 4;

  const int bid = blockIdx.x;               // 1152 = 8 xcd * (18 y * 8 x)
  const int xcd = bid & 7;
  const int local = bid >> 3;
  const int ty = local >> 3;
  const int tx = xcd * 8 + (local & 7);
  const int m0 = tx * 128, n0 = ty * 128;
  const f32x4 fzero = {0.f, 0.f, 0.f, 0.f};

  f32x4 acc[4][4];
  for (int i = 0; i < 4; ++i) for (int j = 0; j < 4; ++j) acc[i][j] = fzero;

  // staging: thread t owns LDS chunks {t + 256*cc}; chunk L=(R,c): R=L>>3,
  // c = t&7 (const). content rule LDS(R,c) = global(R, c ^ (R&7)).
  const int trow = tid >> 3;                      // 0..31 (+32*cc)
  const int tcol = (tid & 7) ^ (trow & 7);        // R&7 == trow&7 (32|cc offset)
  const unsigned short* Asrc = A + (size_t)(m0 + trow) * 768 + tcol * 8;
  const unsigned short* Bsrc = Bt + (size_t)(n0 + trow) * 768 + tcol * 8;
  const int dst0 = tid * 16;                      // dest byte (linear, +4096*cc)

#define STAGE_QKV(s, bidx) do { \
    const unsigned short* as_ = Asrc + (s) * 64; \
    const unsigned short* bs_ = Bsrc + (s) * 64; \
    ASYNC16(as_,            (char*)As[bidx] + dst0); \
    ASYNC16(as_ + 32 * 768, (char*)As[bidx] + dst0 + 4096); \
    ASYNC16(as_ + 64 * 768, (char*)As[bidx] + dst0 + 8192); \
    ASYNC16(as_ + 96 * 768, (char*)As[bidx] + dst0 + 12288); \
    ASYNC16(bs_,            (char*)Bs[bidx] + dst0); \
    ASYNC16(bs_ + 32 * 768, (char*)Bs[bidx] + dst0 + 4096); \
    ASYNC16(bs_ + 64 * 768, (char*)Bs[bidx] + dst0 + 8192); \
    ASYNC16(bs_ + 96 * 768, (char*)Bs[bidx] + dst0 + 12288); \
  } while (0)

  STAGE_QKV(0, 0);

  // read: logical (R, ks, lq) -> LDS chunk ((ks*4+lq) ^ (R&7)); R&7 == lr&7
  const int swz = (lq ^ (lr & 7)) * 16;           // ks=0 chunk byte; ks=1: ^64
  const int arow = (wm * 64 + lr) * 128;          // + i*2048
  const int brow = (wn * 64 + lr) * 128;          // + j*2048

  for (int s = 0; s < 12; ++s) {
    __builtin_amdgcn_s_barrier();                 // all waves done reading buf[(s-1)&1]
    if (s + 1 < 12) {
      STAGE_QKV(s + 1, (s + 1) & 1);
      asm volatile("s_waitcnt vmcnt(8)" ::: "memory");   // stage(s) landed
    } else {
      asm volatile("s_waitcnt vmcnt(0)" ::: "memory");
    }
    __builtin_amdgcn_s_barrier();                 // stage(s) visible to all waves
    __builtin_amdgcn_sched_barrier(0);
    const char* asb = (const char*)As[s & 1];
    const char* bsb = (const char*)Bs[s & 1];
    for (int ks = 0; ks < 2; ++ks) {
      const int cb = swz ^ (ks << 6);
      short8 a[4], b[4];
      for (int i = 0; i < 4; ++i)
        a[i] = *(const short8*)(asb + arow + i * 2048 + cb);
      for (int j = 0; j < 4; ++j)
        b[j] = *(const short8*)(bsb + brow + j * 2048 + cb);
      for (int i = 0; i < 4; ++i)
        for (int j = 0; j < 4; ++j)
          acc[i][j] = __builtin_amdgcn_mfma_f32_16x16x32_bf16(a[i], b[j], acc[i][j], 0, 0, 0);
    }
  }
#undef STAGE_QKV

  const int colbase = n0 + wn * 64;
  const int sec = colbase / 768;                // 0=q, 1=k, 2=v (wave-uniform)
  const float QSCALE = 0.18033688011112042f;    // 0.125 * log2(e)
  for (int j = 0; j < 4; ++j) {
    int col = colbase + j * 16 + lr;
    int cc = col - sec * 768;
    int h = cc >> 6, d = cc & 63;
    float bv = bias[col];
    for (int i = 0; i < 4; ++i) {
      int row0 = m0 + wm * 64 + i * 16 + lq * 4;
      int bidx = row0 >> 10, t0 = row0 & 1023;
      int bh = bidx * 12 + h;
      if (sec == 0) {
        for (int r = 0; r < 4; ++r)
          q[((size_t)bh * 1024 + t0 + r) * 64 + d] = f2b((acc[i][j][r] + bv) * QSCALE);
      } else if (sec == 1) {
        for (int r = 0; r < 4; ++r)
          k[((size_t)bh * 1024 + t0 + r) * 64 + d] = f2b(acc[i][j][r] + bv);
      } else {
        u16x4 pv;
        pv[0] = f2b(acc[i][j][0] + bv);
        pv[1] = f2b(acc[i][j][1] + bv);
        pv[2] = f2b(acc[i][j][2] + bv);
        pv[3] = f2b(acc[i][j][3] + bv);
        *(u16x4*)(vT + ((size_t)bh * 64 + d) * 1024 + t0) = pv;
      }
    }
  }
}

// ---------------- flash attention, dual-Q-tile over one K/V stream ----------------
// R7: double-buffered K/V LDS with Qs-region aliasing (Q lives in registers
// after the prologue, so its 18.4KB LDS is reused as the K/V buffers).
// 1 __syncthreads per k-tile instead of 2 (16 barriers saved/block) and the
// K/V LDS write overlaps compute. Total LDS 45KB -> still 3 blocks/CU.

__global__ __launch_bounds__(256, 3) void attn(
    const unsigned short* __restrict__ q,
    const unsigned short* __restrict__ kk,
    const unsigned short* __restrict__ vT,
    unsigned short* __restrict__ y)         // [8192][768]
{
  __shared__ __attribute__((aligned(16))) char smem[46080];
  unsigned short* KsB0 = (unsigned short*)smem;              // [64][72] 9216B
  unsigned short* KsB1 = (unsigned short*)(smem + 9216);
  unsigned short* VtB0 = (unsigned short*)(smem + 18432);
  unsigned short* VtB1 = (unsigned short*)(smem + 27648);
  unsigned short* Ps   = (unsigned short*)(smem + 36864);    // 4*16*72
  unsigned short* Qs   = (unsigned short*)smem;              // transient [128][72]

  const int tid = threadIdx.x;
  const int w = tid >> 6, lane = tid & 63;
  const int lr = lane & 15, lq = lane >> 4;

  // 768 blocks = 8 xcd * (12 heads * 8 strips); strips of one head adjacent
  const int bid = blockIdx.x;
  const int xcd = bid & 7;
  const int local = bid >> 3;               // 0..95
  const int bh = xcd + 8 * (local >> 3);    // 0..95
  const int qp = local & 7;                 // strip0 tile 0..7
  const int qt1 = 15 - qp;                  // strip1 tile
  const int b = bh / 12, h = bh - b * 12;
  const f32x4 fzero = {0.f, 0.f, 0.f, 0.f};

  unsigned short* Pw = Ps + w * 16 * 72;
  const unsigned short* kbase = kk + (size_t)bh * 65536;
  const unsigned short* vbase = vT + (size_t)bh * 65536;

  // tile-0 K/V prefetch issued first (overlaps Q staging latency)
  const int c0 = tid, c1 = tid + 256;
  short8 kreg[2], vreg[2];
  kreg[0] = *(const short8*)(kbase + (size_t)c0 * 8);
  kreg[1] = *(const short8*)(kbase + (size_t)c1 * 8);
  vreg[0] = *(const short8*)(vbase + (size_t)(c0 >> 3) * 1024 + (c0 & 7) * 8);
  vreg[1] = *(const short8*)(vbase + (size_t)(c1 >> 3) * 1024 + (c1 & 7) * 8);

  {
    const unsigned short* qa = q + ((size_t)bh * 1024 + qp * 64) * 64;
    const unsigned short* qb = q + ((size_t)bh * 1024 + qt1 * 64) * 64;
    for (int c = tid; c < 512; c += 256) {
      int row = c >> 3, d0 = (c & 7) * 8;
      *(short8*)(Qs + row * 72 + d0)        = *(const short8*)(qa + (size_t)c * 8);
      *(short8*)(Qs + (row + 64) * 72 + d0) = *(const short8*)(qb + (size_t)c * 8);
    }
  }
  __syncthreads();
  // Q-hoist: per-wave Q fragments fixed for the whole K-loop
  short8 qf0[2], qf1[2];
  for (int ks = 0; ks < 2; ++ks) {
    qf0[ks] = *(const short8*)(Qs + (w * 16 + lr) * 72 + ks * 32 + lq * 8);
    qf1[ks] = *(const short8*)(Qs + (64 + w * 16 + lr) * 72 + ks * 32 + lq * 8);
  }
  __syncthreads();    // all waves hold Q in regs; Qs region may be clobbered

  const int wo0 = (c0 >> 3) * 72 + (c0 & 7) * 8;
  const int wo1 = (c1 >> 3) * 72 + (c1 & 7) * 8;

  // tile0 -> buf0 (published by the loop's first sync)
  *(short8*)(KsB0 + wo0) = kreg[0];
  *(short8*)(KsB0 + wo1) = kreg[1];
  *(short8*)(VtB0 + wo0) = vreg[0];
  *(short8*)(VtB0 + wo1) = vreg[1];

  const int nkt = qt1 + 1;                  // >= 9
  // prefetch tile1 into regs
  {
    const unsigned short* kp = kbase + 4096;
    const unsigned short* vp = vbase + 64;
    kreg[0] = *(const short8*)(kp + (size_t)c0 * 8);
    kreg[1] = *(const short8*)(kp + (size_t)c1 * 8);
    vreg[0] = *(const short8*)(vp + (size_t)(c0 >> 3) * 1024 + (c0 & 7) * 8);
    vreg[1] = *(const short8*)(vp + (size_t)(c1 >> 3) * 1024 + (c1 & 7) * 8);
  }

  f32x4 o0[4], o1[4];
  float l0[4], l1[4];
  for (int jd = 0; jd < 4; ++jd) { o0[jd] = fzero; o1[jd] = fzero; }
  for (int r = 0; r < 4; ++r) { l0[r] = 0.0f; l1[r] = 0.0f; }

  for (int kt = 0; kt < nkt; ++kt) {
    __syncthreads();   // buf[kt&1] writes visible; buf[(kt+1)&1] reads retired
    const unsigned short* Ks = (kt & 1) ? KsB1 : KsB0;
    const unsigned short* Vt = (kt & 1) ? VtB1 : VtB0;
    if (kt + 1 < nkt) {
      unsigned short* Ksn = (kt & 1) ? KsB0 : KsB1;
      unsigned short* Vtn = (kt & 1) ? VtB0 : VtB1;
      *(short8*)(Ksn + wo0) = kreg[0];
      *(short8*)(Ksn + wo1) = kreg[1];
      *(short8*)(Vtn + wo0) = vreg[0];
      *(short8*)(Vtn + wo1) = vreg[1];
      if (kt + 2 < nkt) {
        const unsigned short* kp = kbase + (size_t)(kt + 2) * 4096;
        const unsigned short* vp = vbase + (size_t)(kt + 2) * 64;
        kreg[0] = *(const short8*)(kp + (size_t)c0 * 8);
        kreg[1] = *(const short8*)(kp + (size_t)c1 * 8);
        vreg[0] = *(const short8*)(vp + (size_t)(c0 >> 3) * 1024 + (c0 & 7) * 8);
        vreg[1] = *(const short8*)(vp + (size_t)(c1 >> 3) * 1024 + (c1 & 7) * 8);
      }
    }

    short8 bk[2][4];
    for (int ks = 0; ks < 2; ++ks)
      for (int j = 0; j < 4; ++j)
        bk[ks][j] = *(const short8*)(Ks + (j * 16 + lr) * 72 + ks * 32 + lq * 8);

    if (kt <= qp) {                         // strip 0 (block-uniform branch)
      f32x4 s[4];
      for (int j = 0; j < 4; ++j) s[j] = fzero;
      __builtin_amdgcn_s_setprio(1);
      for (int ks = 0; ks < 2; ++ks) {
        for (int j = 0; j < 4; ++j)
          s[j] = __builtin_amdgcn_mfma_f32_16x16x32_bf16(qf0[ks], bk[ks][j], s[j], 0, 0, 0);
      }
      __builtin_amdgcn_s_setprio(0);
      if (kt == qp) {
        int rowt = w * 16 + lq * 4;
        for (int j = 0; j < 4; ++j) {
          int colt = j * 16 + lr;
          for (int r = 0; r < 4; ++r)
            if (colt > rowt + r) s[j][r] = -1e30f;
        }
      }
      for (int r = 0; r < 4; ++r) {
        int prow = (lq * 4 + r) * 72;
        float acc = 0.0f;
        for (int j = 0; j < 4; ++j) {
          float p = __builtin_amdgcn_exp2f(s[j][r]);
          acc += p;
          union { float f; unsigned int u; } cv; cv.f = p;
          Pw[prow + j * 16 + lr] = (unsigned short)((cv.u + 0x8000u) >> 16);
        }
        l0[r] += acc;
      }
      __builtin_amdgcn_s_setprio(1);
      for (int ks = 0; ks < 2; ++ks) {
        short8 ap = *(const short8*)(Pw + lr * 72 + ks * 32 + lq * 8);
        short8 bv[4];
        for (int jd = 0; jd < 4; ++jd)
          bv[jd] = *(const short8*)(Vt + (jd * 16 + lr) * 72 + ks * 32 + lq * 8);
        for (int jd = 0; jd < 4; ++jd)
          o0[jd] = __builtin_amdgcn_mfma_f32_16x16x32_bf16(ap, bv[jd], o0[jd], 0, 0, 0);
      }
      __builtin_amdgcn_s_setprio(0);
    }

    {                                       // strip 1 (always active)
      f32x4 s[4];
      for (int j = 0; j < 4; ++j) s[j] = fzero;
      __builtin_amdgcn_s_setprio(1);
      for (int ks = 0; ks < 2; ++ks) {
        for (int j = 0; j < 4; ++j)
          s[j] = __builtin_amdgcn_mfma_f32_16x16x32_bf16(qf1[ks], bk[ks][j], s[j], 0, 0, 0);
      }
      __builtin_amdgcn_s_setprio(0);
      if (kt == qt1) {
        int rowt = w * 16 + lq * 4;
        for (int j = 0; j < 4; ++j) {
          int colt = j * 16 + lr;
          for (int r = 0; r < 4; ++r)
            if (colt > rowt + r) s[j][r] = -1e30f;
        }
      }
      for (int r = 0; r < 4; ++r) {
        int prow = (lq * 4 + r) * 72;
        float acc = 0.0f;
        for (int j = 0; j < 4; ++j) {
          float p = __builtin_amdgcn_exp2f(s[j][r]);
          acc += p;
          union { float f; unsigned int u; } cv; cv.f = p;
          Pw[prow + j * 16 + lr] = (unsigned short)((cv.u + 0x8000u) >> 16);
        }
        l1[r] += acc;
      }
      __builtin_amdgcn_s_setprio(1);
      for (int ks = 0; ks < 2; ++ks) {
        short8 ap = *(const short8*)(Pw + lr * 72 + ks * 32 + lq * 8);
        short8 bv[4];
        for (int jd = 0; jd < 4; ++jd)
          bv[jd] = *(const short8*)(Vt + (jd * 16 + lr) * 72 + ks * 32 + lq * 8);
        for (int jd = 0; jd < 4; ++jd)
          o1[jd] = __builtin_amdgcn_mfma_f32_16x16x32_bf16(ap, bv[jd], o1[jd], 0, 0, 0);
      }
      __builtin_amdgcn_s_setprio(0);
    }
  }

  for (int r = 0; r < 4; ++r) {
    float a0 = l0[r], a1 = l1[r];
    for (int off = 1; off < 16; off <<= 1) {
      a0 += __shfl_xor(a0, off, 16);
      a1 += __shfl_xor(a1, off, 16);
    }
    l0[r] = 1.0f / a0;
    l1[r] = 1.0f / a1;
  }
  int t0 = qp * 64 + w * 16 + lq * 4;
  int t1 = qt1 * 64 + w * 16 + lq * 4;
  for (int jd = 0; jd < 4; ++jd) {
    int d = jd * 16 + lr;
    for (int r = 0; r < 4; ++r) {
      y[((size_t)b * 1024 + t0 + r) * 768 + h * 64 + d] = f2b(o0[jd][r] * l0[r]);
      y[((size_t)b * 1024 + t1 + r) * 768 + h * 64 + d] = f2b(o1[jd][r] * l1[r]);
    }
  }
}

// ---------------- GEMM 2: out = y @ w_proj + b ----------------
// R3 structure unchanged (swizzled BK=64, 2-deep, vmcnt(6)).

__global__ __launch_bounds__(256, 3) void gemm_proj(
    const unsigned short* __restrict__ A,   // y [8192][768]
    const unsigned short* __restrict__ Bt,  // wpT [768][768]
    const float* __restrict__ bias,         // [768]
    float* __restrict__ out)                // [8192][768] fp32
{
  __shared__ unsigned short As[2][64 * 64];   // 8KB sub-tiles
  __shared__ unsigned short Bs[2][128 * 64];  // 16KB sub-tiles
  const int tid = threadIdx.x;
  const int w = tid >> 6, lane = tid & 63;
  const int wm = w >> 1, wn = w & 1;        // wave-tile 32 x 64
  const int lr = lane & 15, lq = lane >> 4;

  // 768 blocks = 8 xcd * (6 y * 16 x)
  const int bid = blockIdx.x;
  const int xcd = bid & 7;
  const int local = bid >> 3;               // 0..95
  const int ty = local >> 4;                // 0..5
  const int tx = xcd * 16 + (local & 15);   // 0..127
  const int m0 = tx * 64, n0 = ty * 128;
  const f32x4 fzero = {0.f, 0.f, 0.f, 0.f};

  f32x4 acc[2][4];
  for (int i = 0; i < 2; ++i) for (int j = 0; j < 4; ++j) acc[i][j] = fzero;

  const int trow = tid >> 3;                // 0..31
  const int tcol = (tid & 7) ^ (trow & 7);
  const unsigned short* Asrc = A + (size_t)(m0 + trow) * 768 + tcol * 8;
  const unsigned short* Bsrc = Bt + (size_t)(n0 + trow) * 768 + tcol * 8;
  const int dst0 = tid * 16;

#define STAGE_PROJ(s, bidx) do { \
    const unsigned short* as_ = Asrc + (s) * 64; \
    const unsigned short* bs_ = Bsrc + (s) * 64; \
    ASYNC16(as_,            (char*)As[bidx] + dst0); \
    ASYNC16(as_ + 32 * 768, (char*)As[bidx] + dst0 + 4096); \
    ASYNC16(bs_,            (char*)Bs[bidx] + dst0); \
    ASYNC16(bs_ + 32 * 768, (char*)Bs[bidx] + dst0 + 4096); \
    ASYNC16(bs_ + 64 * 768, (char*)Bs[bidx] + dst0 + 8192); \
    ASYNC16(bs_ + 96 * 768, (char*)Bs[bidx] + dst0 + 12288); \
  } while (0)

  STAGE_PROJ(0, 0);

  const int swz = (lq ^ (lr & 7)) * 16;
  const int arow = (wm * 32 + lr) * 128;    // + i*2048
  const int brow = (wn * 64 + lr) * 128;    // + j*2048

  for (int s = 0; s < 12; ++s) {
    __builtin_amdgcn_s_barrier();
    if (s + 1 < 12) {
      STAGE_PROJ(s + 1, (s + 1) & 1);
      asm volatile("s_waitcnt vmcnt(6)" ::: "memory");
    } else {
      asm volatile("s_waitcnt vmcnt(0)" ::: "memory");
    }
    __builtin_amdgcn_s_barrier();
    __builtin_amdgcn_sched_barrier(0);
    const char* asb = (const char*)As[s & 1];
    const char* bsb = (const char*)Bs[s & 1];
    for (int ks = 0; ks < 2; ++ks) {
      const int cb = swz ^ (ks << 6);
      short8 a[2], b[4];
      for (int i = 0; i < 2; ++i)
        a[i] = *(const short8*)(asb + arow + i * 2048 + cb);
      for (int j = 0; j < 4; ++j)
        b[j] = *(const short8*)(bsb + brow + j * 2048 + cb);
      for (int i = 0; i < 2; ++i)
        for (int j = 0; j < 4; ++j)
          acc[i][j] = __builtin_amdgcn_mfma_f32_16x16x32_bf16(a[i], b[j], acc[i][j], 0, 0, 0);
    }
  }
#undef STAGE_PROJ

  for (int j = 0; j < 4; ++j) {
    int col = n0 + wn * 64 + j * 16 + lr;
    float bv = bias[col];
    for (int i = 0; i < 2; ++i) {
      int row0 = m0 + wm * 32 + i * 16 + lq * 4;
      for (int r = 0; r < 4; ++r)
        out[(size_t)(row0 + r) * 768 + col] = acc[i][j][r] + bv;
    }
  }
}

// ---------------- launch ----------------

extern "C" void kernel_launch(void* const* d_in, const int* in_sizes, int n_in,
                              void* d_out, int out_size, void* d_ws, size_t ws_size,
                              hipStream_t stream) {
  const float* x      = (const float*)d_in[0];
  const float* w_attn = (const float*)d_in[1];
  const float* b_attn = (const float*)d_in[2];
  const float* w_proj = (const float*)d_in[3];
  const float* b_proj = (const float*)d_in[4];
  float* out = (float*)d_out;

  char* p = (char*)d_ws;
  unsigned short* xb  = (unsigned short*)p; p += (size_t)8192 * 768 * 2;
  unsigned short* waT = (unsigned short*)p; p += (size_t)2304 * 768 * 2;
  unsigned short* wpT = (unsigned short*)p; p += (size_t)768 * 768 * 2;
  unsigned short* qb  = (unsigned short*)p; p += (size_t)96 * 1024 * 64 * 2;
  unsigned short* kb  = (unsigned short*)p; p += (size_t)96 * 1024 * 64 * 2;
  unsigned short* vTb = (unsigned short*)p; p += (size_t)96 * 64 * 1024 * 2;
  unsigned short* yb  = (unsigned short*)p; p += (size_t)8192 * 768 * 2;

  prep<<<3648, 256, 0, stream>>>(x, xb, w_attn, waT, w_proj, wpT);
  gemm_qkv<<<1152, 256, 0, stream>>>(xb, waT, b_attn, qb, kb, vTb);
  attn<<<768, 256, 0, stream>>>(qb, kb, vTb, yb);
  gemm_proj<<<768, 256, 0, stream>>>(yb, wpT, b_proj, out);
}